// Round 13
// baseline (43657.690 us; speedup 1.0000x reference)
//
#include <hip/hip_runtime.h>
#include <stdint.h>

typedef unsigned short u16;
typedef unsigned int   u32;
typedef _Float16 half2v __attribute__((ext_vector_type(2)));

#define L2E 1.4426950408889634f
#define TWO_L2E 2.8853900817779268f

__device__ __forceinline__ float bf2f(u16 b){ return __uint_as_float(((u32)b) << 16); }
__device__ __forceinline__ float ldf(const void* p, size_t i, int flag){
  return flag ? ((const float*)p)[i] : bf2f(((const u16*)p)[i]);
}
__device__ __forceinline__ float rcpfast(float x){
#if __has_builtin(__builtin_amdgcn_rcpf)
  return __builtin_amdgcn_rcpf(x);
#else
  return 1.0f / x;
#endif
}
__device__ __forceinline__ float exp2fast(float x){
#if __has_builtin(__builtin_amdgcn_exp2f)
  return __builtin_amdgcn_exp2f(x);
#else
  return exp2f(x);
#endif
}
__device__ __forceinline__ float fdot2f(u32 a, u32 b, float c){
#if __has_builtin(__builtin_amdgcn_fdot2)
  return __builtin_amdgcn_fdot2(__builtin_bit_cast(half2v, a), __builtin_bit_cast(half2v, b), c, false);
#else
  half2v ha = __builtin_bit_cast(half2v, a), hb = __builtin_bit_cast(half2v, b);
  return c + (float)ha[0]*(float)hb[0] + (float)ha[1]*(float)hb[1];
#endif
}
__device__ __forceinline__ u32 pkh2(float lo, float hi){
  half2v h; h[0] = (_Float16)lo; h[1] = (_Float16)hi;
  return __builtin_bit_cast(u32, h);
}
__device__ __forceinline__ u16 f2h16(float f){
  _Float16 h = (_Float16)f;
  return __builtin_bit_cast(u16, h);
}
__device__ __forceinline__ float h16f(u16 h){
  return (float)__builtin_bit_cast(_Float16, h);
}

// ---------------- sentinel ----------------
__global__ void k_sentinelf(float* __restrict__ out, int n, float val){
  int i = blockIdx.x*256 + threadIdx.x;
  if(i < n) out[i] = val;
}

// ---------------- dtype detection + canonicalize ----------------
__global__ void k_detect(const u16* __restrict__ p, int n, int* __restrict__ flag){
  __shared__ int cnt;
  if(threadIdx.x == 0) cnt = 0;
  __syncthreads();
  int c = 0;
  for(int i = threadIdx.x; i < n; i += 256){
    int e = (p[i] >> 7) & 0xFF;
    c += (e >= 112 && e <= 142) ? 1 : 0;
  }
  atomicAdd(&cnt, c);
  __syncthreads();
  if(threadIdx.x == 0) *flag = (cnt >= (n/10)*9) ? 0 : 1;
}
__global__ void k_convf(const void* __restrict__ src, float* __restrict__ dst, int n,
                        const int* __restrict__ flag){
  int i = blockIdx.x*256 + threadIdx.x;
  if(i < n) dst[i] = ldf(src, i, *flag);
}

// ---------------- packs ----------------
__global__ void k_pack_wh2(const void* __restrict__ Wh, u32* __restrict__ out,
                           const int* __restrict__ flag){
  int i = blockIdx.x*256 + threadIdx.x;
  if(i >= 2*128*256) return;
  int d = i >> 15, k2 = (i >> 8) & 127, a = i & 255;
  float lo = ldf(Wh, ((size_t)d*256 + 2*k2    )*256 + a, *flag);
  float hi = ldf(Wh, ((size_t)d*256 + 2*k2 + 1)*256 + a, *flag);
  out[i] = pkh2(lo, hi);
}
__global__ void k_pack_wc2(const void* __restrict__ Whh, const void* __restrict__ Wih,
                           u32* __restrict__ out, const int* __restrict__ flag){
  int i = blockIdx.x*256 + threadIdx.x;
  if(i >= 2*128*2304) return;
  int d = i / (128*2304), r = i % (128*2304);
  int k2 = r / 2304, j = r % 2304;
  int k = 2*k2;
  float lo, hi;
  if(j < 768){
    lo = ldf(Whh, ((size_t)d*768 + j)*256 + k,     *flag);
    hi = ldf(Whh, ((size_t)d*768 + j)*256 + k + 1, *flag);
  } else if(j < 1536){
    lo = ldf(Wih, ((size_t)d*768 + (j-768))*512 + 256 + k,     *flag);
    hi = ldf(Wih, ((size_t)d*768 + (j-768))*512 + 256 + k + 1, *flag);
  } else {
    lo = ldf(Wih, ((size_t)d*768 + (j-1536))*512 + k,     *flag);
    hi = ldf(Wih, ((size_t)d*768 + (j-1536))*512 + k + 1, *flag);
  }
  out[i] = pkh2(lo, hi);
}
__global__ void k_pack_h2(const void* __restrict__ src, u32* __restrict__ out, int n2,
                          const int* __restrict__ flag){
  int i = blockIdx.x*256 + threadIdx.x;
  if(i >= n2) return;
  out[i] = pkh2(ldf(src, 2*(size_t)i, *flag), ldf(src, 2*(size_t)i + 1, *flag));
}
__global__ void k_pack_wiht(const void* __restrict__ Wih, float* __restrict__ out,
                            const int* __restrict__ flag){
  int i = blockIdx.x*256 + threadIdx.x;
  if(i >= 2*256*768) return;
  int d = i / 196608, r = i % 196608;
  int k = r / 768, j = r % 768;
  out[i] = ldf(Wih, ((size_t)d*768 + j)*512 + k, *flag);
}

// ---------------- GEMM C = A@B, fp16 out. MODE 0: plain; MODE 1: clamp(exp2(v*2log2e)) ----
template<int MODE>
__global__ __launch_bounds__(256)
void k_gemm_h16(const float* __restrict__ A, int lda,
                const float* __restrict__ B, int ldb,
                u16* __restrict__ C, int N, int K)
{
  __shared__ float As[64][17];
  __shared__ float Bs[16][65];
  const int m0 = blockIdx.x * 64, n0 = blockIdx.y * 64;
  const int tid = threadIdx.x;
  const int arow = tid >> 2, acol = (tid & 3) * 4;
  const int brow = tid >> 4, bcol = (tid & 15) * 4;
  const int ty = tid >> 4, tx = tid & 15;
  float acc[4][4];
  #pragma unroll
  for(int i=0;i<4;++i)
    #pragma unroll
    for(int j=0;j<4;++j) acc[i][j] = 0.f;
  for(int k0 = 0; k0 < K; k0 += 16){
    float4 a4 = *(const float4*)(A + (size_t)(m0 + arow)*lda + k0 + acol);
    As[arow][acol+0] = a4.x; As[arow][acol+1] = a4.y;
    As[arow][acol+2] = a4.z; As[arow][acol+3] = a4.w;
    float4 b4 = *(const float4*)(B + (size_t)(k0 + brow)*ldb + n0 + bcol);
    Bs[brow][bcol+0] = b4.x; Bs[brow][bcol+1] = b4.y;
    Bs[brow][bcol+2] = b4.z; Bs[brow][bcol+3] = b4.w;
    __syncthreads();
    #pragma unroll
    for(int kk = 0; kk < 16; ++kk){
      float ar[4], br[4];
      #pragma unroll
      for(int i=0;i<4;++i) ar[i] = As[ty*4+i][kk];
      #pragma unroll
      for(int j=0;j<4;++j) br[j] = Bs[kk][tx*4+j];
      #pragma unroll
      for(int i=0;i<4;++i)
        #pragma unroll
        for(int j=0;j<4;++j) acc[i][j] = fmaf(ar[i], br[j], acc[i][j]);
    }
    __syncthreads();
  }
  #pragma unroll
  for(int i=0;i<4;++i)
    #pragma unroll
    for(int j=0;j<4;++j){
      float v = acc[i][j];
      if(MODE==1){ v = exp2fast(v * TWO_L2E); v = fminf(v, 65504.f); }
      C[(size_t)(m0 + ty*4 + i)*N + n0 + tx*4 + j] = f2h16(v);
    }
}

// ---------------- scan v7 (gix variant): k_scan5 structure + Wh-in-LDS + 3-pass R_A ----
// dynamic LDS layout (bytes):
//   0      Whl    [128][256] u32   131072
//   131072 part   [16][256]  f32    16384
//   147456 ghgi   [1536]     f32     6144
//   153600 F      [256]      f32     1024
//   154624 h_l    [256]      f32     1024
//   155648 h2     [128]      u32      512
//   156160 c2     [128]      u32      512
//   156672 esum_w [64]       f32      256
//   156928 svp    [4]        f32       16
#define SCAN7_LDS 156944
__global__ __launch_bounds__(1024)
void k_scan7(const u16* __restrict__ E16,    // [2][16384][256] fp16 e^{2P} clamped
             const u16* __restrict__ qx16,   // [2][16384][256] fp16 x@Wi
             const u32* __restrict__ Wh2,    // [2][128][256]
             const u32* __restrict__ Wc2,    // [2][128][2304] (cols 0..1535 used)
             const u16* __restrict__ gix16,  // [2][16384][768]
             const u32* __restrict__ memh2,  // [32][512][128]
             const float* __restrict__ vf,
             const float* __restrict__ bihf,
             const float* __restrict__ bhhf,
             float* __restrict__ ys)         // [32][512][512] f32 = d_out
{
  extern __shared__ char smem[];
  u32*   Whl    = (u32*)(smem);
  float* part   = (float*)(smem + 131072);
  float* ghgi   = (float*)(smem + 147456);
  float* F      = (float*)(smem + 153600);
  float* h_l    = (float*)(smem + 154624);
  u32*   h2     = (u32*)(smem + 155648);
  u32*   c2     = (u32*)(smem + 156160);
  float* esum_w = (float*)(smem + 156672);
  float* svp_p  = (float*)(smem + 156928);

  const int tid = threadIdx.x;
  const int p = blockIdx.x, d = p >> 5, b = p & 31;
  const int lane = tid & 63, wave = tid >> 6;
  const int g = lane >> 4, l = lane & 15;

  const u16* Eb   = E16   + ((size_t)d*16384 + (size_t)b*512)*256;
  const u16* qxb  = qx16  + ((size_t)d*16384 + (size_t)b*512)*256;
  const u32* Whd  = Wh2   + (size_t)d*128*256;
  const u32* Wcd  = Wc2   + (size_t)d*128*2304;
  const u16* gixb = gix16 + ((size_t)d*16384 + (size_t)b*512)*768;
  const u32* mhb  = memh2 + (size_t)b*512*128;

  // ---- prologue: Wh -> LDS (once); h=0; v slice; svp
  {
    const uint4* wg = (const uint4*)Whd;   // 8192 uint4
    uint4* wdst = (uint4*)Whl;
    #pragma unroll
    for(int i = 0; i < 8; ++i) wdst[tid + i*1024] = wg[tid + i*1024];
  }
  if(tid < 256) h_l[tid] = 0.f;
  if(tid < 128) h2[tid] = 0u;
  float vr[16];
  {
    const float* vp = vf + d*256 + l*16;
    *(float4*)&vr[0]  = *(const float4*)(vp);
    *(float4*)&vr[4]  = *(const float4*)(vp + 4);
    *(float4*)&vr[8]  = *(const float4*)(vp + 8);
    *(float4*)&vr[12] = *(const float4*)(vp + 12);
  }
  if(tid == 0){
    float s = 0.f;
    for(int i=0;i<256;++i) s += vf[d*256 + i];
    svp_p[0] = s * L2E;
  }
  float bh0=0,bh1=0,bh2v=0,bi0=0,bi1=0,bi2=0;
  if(tid < 256){
    bh0  = bhhf[d*768 + tid];       bi0 = bihf[d*768 + tid];
    bh1  = bhhf[d*768 + 256 + tid]; bi1 = bihf[d*768 + 256 + tid];
    bh2v = bhhf[d*768 + 512 + tid]; bi2 = bihf[d*768 + 512 + tid];
  }
  __syncthreads();

  auto gdot = [&](int col, const u32* s2){
    const u32* wp = Wcd + col;
    float a0=0.f, a1=0.f, a2=0.f, a3=0.f;
    #pragma unroll 4
    for(int k0=0;k0<32;++k0){
      uint4 s4 = *(const uint4*)&s2[4*k0];
      a0 = fdot2f(wp[(size_t)(4*k0    )*2304], s4.x, a0);
      a1 = fdot2f(wp[(size_t)(4*k0 + 1)*2304], s4.y, a1);
      a2 = fdot2f(wp[(size_t)(4*k0 + 2)*2304], s4.z, a2);
      a3 = fdot2f(wp[(size_t)(4*k0 + 3)*2304], s4.w, a3);
    }
    ghgi[col] = (a0+a1)+(a2+a3);
  };

  for(int step = 0; step < 512; ++step){
    const int tx = d ? (511 - step) : step;

    // ---- S0: q partials (h@Wh from LDS). kq=tid>>8 (4 quarters of 32 k2)
    {
      const int a = tid & 255, kq = tid >> 8;
      const u32* wp = Whl + (size_t)(kq*32)*256 + a;
      float q0=0.f,q1=0.f,q2=0.f,q3=0.f;
      #pragma unroll
      for(int i0=0;i0<8;++i0){
        uint4 hv = *(const uint4*)&h2[kq*32 + 4*i0];
        q0 = fdot2f(wp[(size_t)(4*i0    )*256], hv.x, q0);
        q1 = fdot2f(wp[(size_t)(4*i0 + 1)*256], hv.y, q1);
        q2 = fdot2f(wp[(size_t)(4*i0 + 2)*256], hv.z, q2);
        q3 = fdot2f(wp[(size_t)(4*i0 + 3)*256], hv.w, q3);
      }
      part[kq*256 + a] = (q0+q1)+(q2+q3);
    }
    __syncthreads();
    // ---- S1: F = e^{2q}
    if(tid < 256){
      float q = h16f(qxb[(size_t)tx*256 + tid])
              + part[tid] + part[256+tid] + part[512+tid] + part[768+tid];
      F[tid] = exp2fast(q * TWO_L2E);
    }
    __syncthreads();

    // ---- S2: h-col gemv (768 threads) overlapped with 3-pass R_A (all threads)
    {
      if(tid < 768) gdot(tid, h2);

      float Fr[16];
      {
        const float* fp = F + l*16;
        *(float4*)&Fr[0]  = *(const float4*)(fp);
        *(float4*)&Fr[4]  = *(const float4*)(fp + 4);
        *(float4*)&Fr[8]  = *(const float4*)(fp + 8);
        *(float4*)&Fr[12] = *(const float4*)(fp + 12);
      }

      // pass 1: per-row partial scores u[8] (4 independent accumulators)
      float u[8];
      #pragma unroll
      for(int it=0; it<8; ++it){
        const int m = wave*32 + it*4 + g;
        uint4 e0 = *(const uint4*)(Eb + (size_t)m*256 + l*16);
        uint4 e1 = *(const uint4*)(Eb + (size_t)m*256 + l*16 + 8);
        float ua=0.f, ub=0.f, uc=0.f, ud=0.f;
        #define RA_PAIR(EU, J, ACC) { \
          half2v hh = __builtin_bit_cast(half2v, EU); \
          float t0 = rcpfast(fmaf((float)hh[0], Fr[2*(J)],   1.f)); \
          float t1 = rcpfast(fmaf((float)hh[1], Fr[2*(J)+1], 1.f)); \
          ACC = fmaf(vr[2*(J)], t0, ACC); ACC = fmaf(vr[2*(J)+1], t1, ACC); }
        RA_PAIR(e0.x,0,ua) RA_PAIR(e0.y,1,ub) RA_PAIR(e0.z,2,uc) RA_PAIR(e0.w,3,ud)
        RA_PAIR(e1.x,4,ua) RA_PAIR(e1.y,5,ub) RA_PAIR(e1.z,6,uc) RA_PAIR(e1.w,7,ud)
        #undef RA_PAIR
        u[it] = (ua+ub)+(uc+ud);
      }
      // pass 2: shfl-reduce all rows (independent chains pipeline in DS)
      #pragma unroll
      for(int it=0; it<8; ++it) u[it] += __shfl_xor(u[it], 1, 64);
      #pragma unroll
      for(int it=0; it<8; ++it) u[it] += __shfl_xor(u[it], 2, 64);
      #pragma unroll
      for(int it=0; it<8; ++it) u[it] += __shfl_xor(u[it], 4, 64);
      #pragma unroll
      for(int it=0; it<8; ++it) u[it] += __shfl_xor(u[it], 8, 64);
      const float svp = svp_p[0];
      float es[8];
      float esum0 = 0.f, esum1 = 0.f;
      #pragma unroll
      for(int it=0; it<8; ++it){
        es[it] = exp2fast(fmaf(u[it], -TWO_L2E, svp));
        if(it & 1) esum1 += es[it]; else esum0 += es[it];
      }
      // pass 3: context accumulation with es
      float cr[16];
      #pragma unroll
      for(int i=0;i<16;++i) cr[i] = 0.f;
      #pragma unroll
      for(int it=0; it<8; ++it){
        const int m = wave*32 + it*4 + g;
        uint4 m0 = *(const uint4*)(mhb + (size_t)m*128 + l*8);
        uint4 m1 = *(const uint4*)(mhb + (size_t)m*128 + l*8 + 4);
        const float e = es[it];
        #define RC_PAIR(MU, J) { \
          half2v hh = __builtin_bit_cast(half2v, MU); \
          cr[2*(J)]   = fmaf((float)hh[0], e, cr[2*(J)]); \
          cr[2*(J)+1] = fmaf((float)hh[1], e, cr[2*(J)+1]); }
        RC_PAIR(m0.x,0) RC_PAIR(m0.y,1) RC_PAIR(m0.z,2) RC_PAIR(m0.w,3)
        RC_PAIR(m1.x,4) RC_PAIR(m1.y,5) RC_PAIR(m1.z,6) RC_PAIR(m1.w,7)
        #undef RC_PAIR
      }
      #pragma unroll
      for(int i=0;i<16;++i){
        cr[i] += __shfl_xor(cr[i], 16, 64);
        cr[i] += __shfl_xor(cr[i], 32, 64);
      }
      if(lane < 16){
        float* pp = part + wave*256 + l*16;
        *(float4*)(pp)      = make_float4(cr[0],  cr[1],  cr[2],  cr[3]);
        *(float4*)(pp + 4)  = make_float4(cr[4],  cr[5],  cr[6],  cr[7]);
        *(float4*)(pp + 8)  = make_float4(cr[8],  cr[9],  cr[10], cr[11]);
        *(float4*)(pp + 12) = make_float4(cr[12], cr[13], cr[14], cr[15]);
      }
      if(l == 0) esum_w[wave*4 + g] = esum0 + esum1;
    }
    __syncthreads();

    // ---- S3: combine c + pack c2 (tid<128, 2 columns each)
    if(tid < 128){
      float rs = 0.f;
      #pragma unroll
      for(int i2=0;i2<64;++i2) rs += esum_w[i2];
      rs = rcpfast(rs);
      float lo = 0.f, hi = 0.f;
      #pragma unroll
      for(int w=0; w<16; ++w){
        lo += part[w*256 + 2*tid];
        hi += part[w*256 + 2*tid + 1];
      }
      c2[tid] = pkh2(lo*rs, hi*rs);
    }
    __syncthreads();

    // ---- S4: c-col gemv (768)
    if(tid < 768) gdot(768 + tid, c2);
    __syncthreads();

    // ---- S5: gates + h update
    if(tid < 256){
      const int j = tid;
      const u16* gxp = gixb + (size_t)tx*768;
      float hr  = ghgi[j]       + bh0;
      float hz  = ghgi[256 + j] + bh1;
      float hn  = ghgi[512 + j] + bh2v;
      float ir  = ghgi[768 + j]       + h16f(gxp[j])       + bi0;
      float iz  = ghgi[768 + 256 + j] + h16f(gxp[256 + j]) + bi1;
      float inn = ghgi[768 + 512 + j] + h16f(gxp[512 + j]) + bi2;
      float r = rcpfast(1.f + exp2fast(-(ir + hr) * L2E));
      float z = rcpfast(1.f + exp2fast(-(iz + hz) * L2E));
      float narg = inn + r*hn;
      float n = 1.f - 2.f*rcpfast(1.f + exp2fast(narg * TWO_L2E));
      float hnew = (1.f - z)*n + z*h_l[j];
      h_l[j] = hnew;
      ys[((size_t)b*512 + tx)*512 + d*256 + j] = hnew;
    }
    __syncthreads();

    // ---- S6: pack h2
    if(tid < 128) h2[tid] = pkh2(h_l[2*tid], h_l[2*tid + 1]);
    __syncthreads();
  }
}

// ---------------- scan v5b (no-gix fallback, unchanged from R11 variant B) ----------------
__global__ __launch_bounds__(1024)
void k_scan5b(const u16* __restrict__ E16, const u16* __restrict__ qx16,
              const u32* __restrict__ Wh2, const u32* __restrict__ Wc2,
              const u32* __restrict__ xh2, const u32* __restrict__ memh2,
              const float* __restrict__ vf, const float* __restrict__ bihf,
              const float* __restrict__ bhhf, float* __restrict__ ys)
{
  __shared__ float h_l[256];
  __shared__ __align__(16) u32 h2[128];
  __shared__ __align__(16) u32 c2[128];
  __shared__ __align__(16) u32 x2[128];
  __shared__ __align__(16) float F[256];
  __shared__ __align__(16) float part[4096];
  __shared__ float ghgi[2304];
  __shared__ float esum_w[64];
  __shared__ float svp_sh;

  const int tid = threadIdx.x;
  const int p = blockIdx.x, d = p >> 5, b = p & 31;
  const int lane = tid & 63, wave = tid >> 6;
  const int g = lane >> 4, l = lane & 15;

  const u16* Eb  = E16  + ((size_t)d*16384 + (size_t)b*512)*256;
  const u16* qxb = qx16 + ((size_t)d*16384 + (size_t)b*512)*256;
  const u32* Whd = Wh2  + (size_t)d*128*256;
  const u32* Wcd = Wc2  + (size_t)d*128*2304;
  const u32* xhb = xh2  + (size_t)b*512*128;
  const u32* mhb = memh2 + (size_t)b*512*128;

  if(tid < 256){ h_l[tid] = 0.f; part[tid] = vf[d*256 + tid]; }
  if(tid < 128){
    h2[tid] = 0u;
    int tx0 = d ? 511 : 0;
    x2[tid] = xhb[(size_t)tx0*128 + tid];
  }
  float vr[16];
  {
    const float* vp = vf + d*256 + l*16;
    *(float4*)&vr[0]  = *(const float4*)(vp);
    *(float4*)&vr[4]  = *(const float4*)(vp + 4);
    *(float4*)&vr[8]  = *(const float4*)(vp + 8);
    *(float4*)&vr[12] = *(const float4*)(vp + 12);
  }
  float bh0=0,bh1=0,bh2v=0,bi0=0,bi1=0,bi2=0;
  if(tid < 256){
    bh0  = bhhf[d*768 + tid];       bi0 = bihf[d*768 + tid];
    bh1  = bhhf[d*768 + 256 + tid]; bi1 = bihf[d*768 + 256 + tid];
    bh2v = bhhf[d*768 + 512 + tid]; bi2 = bihf[d*768 + 512 + tid];
  }
  __syncthreads();
  if(tid == 0){ float s=0.f; for(int i=0;i<256;++i) s += part[i]; svp_sh = s * L2E; }
  __syncthreads();

  auto gdot = [&](int col, const u32* s2){
    const u32* wp = Wcd + col;
    float a0=0.f, a1=0.f, a2=0.f, a3=0.f;
    #pragma unroll 4
    for(int k0=0;k0<32;++k0){
      uint4 s4 = *(const uint4*)&s2[4*k0];
      a0 = fdot2f(wp[(size_t)(4*k0    )*2304], s4.x, a0);
      a1 = fdot2f(wp[(size_t)(4*k0 + 1)*2304], s4.y, a1);
      a2 = fdot2f(wp[(size_t)(4*k0 + 2)*2304], s4.z, a2);
      a3 = fdot2f(wp[(size_t)(4*k0 + 3)*2304], s4.w, a3);
    }
    ghgi[col] = (a0+a1)+(a2+a3);
  };

  for(int step = 0; step < 512; ++step){
    const int tx = d ? (511 - step) : step;
    {
      const int a = tid & 255, kq = tid >> 8;
      const u32* wp = Whd + (size_t)(kq*32)*256 + a;
      float q0=0.f,q1=0.f,q2=0.f,q3=0.f;
      #pragma unroll
      for(int i0=0;i0<8;++i0){
        uint4 hv = *(const uint4*)&h2[kq*32 + 4*i0];
        q0 = fdot2f(wp[(size_t)(4*i0    )*256], hv.x, q0);
        q1 = fdot2f(wp[(size_t)(4*i0 + 1)*256], hv.y, q1);
        q2 = fdot2f(wp[(size_t)(4*i0 + 2)*256], hv.z, q2);
        q3 = fdot2f(wp[(size_t)(4*i0 + 3)*256], hv.w, q3);
      }
      part[kq*256 + a] = (q0+q1)+(q2+q3);
    }
    __syncthreads();
    if(tid < 256){
      float q = h16f(qxb[(size_t)tx*256 + tid])
              + part[tid] + part[256+tid] + part[512+tid] + part[768+tid];
      F[tid] = exp2fast(q * TWO_L2E);
    }
    __syncthreads();
    {
      if(tid < 768) gdot(tid, h2);
      if(tid >= 768) gdot(1536 + (tid - 768), x2);
      if(tid < 512)  gdot(1792 + tid, x2);

      float Fr[16];
      {
        const float* fp = F + l*16;
        *(float4*)&Fr[0]  = *(const float4*)(fp);
        *(float4*)&Fr[4]  = *(const float4*)(fp + 4);
        *(float4*)&Fr[8]  = *(const float4*)(fp + 8);
        *(float4*)&Fr[12] = *(const float4*)(fp + 12);
      }
      float cr[16];
      #pragma unroll
      for(int i=0;i<16;++i) cr[i] = 0.f;
      float esum = 0.f;
      const float svp = svp_sh;
      #pragma unroll 2
      for(int it=0; it<8; ++it){
        const int m = wave*32 + it*4 + g;
        uint4 e0 = *(const uint4*)(Eb + (size_t)m*256 + l*16);
        uint4 e1 = *(const uint4*)(Eb + (size_t)m*256 + l*16 + 8);
        float u = 0.f;
        {
          #define RA_PAIR(EU, J) { \
            half2v hh = __builtin_bit_cast(half2v, EU); \
            float t0 = rcpfast(fmaf((float)hh[0], Fr[2*(J)],   1.f)); \
            float t1 = rcpfast(fmaf((float)hh[1], Fr[2*(J)+1], 1.f)); \
            u = fmaf(vr[2*(J)], t0, u); u = fmaf(vr[2*(J)+1], t1, u); }
          RA_PAIR(e0.x,0) RA_PAIR(e0.y,1) RA_PAIR(e0.z,2) RA_PAIR(e0.w,3)
          RA_PAIR(e1.x,4) RA_PAIR(e1.y,5) RA_PAIR(e1.z,6) RA_PAIR(e1.w,7)
          #undef RA_PAIR
        }
        u += __shfl_xor(u, 1, 64);
        u += __shfl_xor(u, 2, 64);
        u += __shfl_xor(u, 4, 64);
        u += __shfl_xor(u, 8, 64);
        float es = exp2fast(fmaf(u, -TWO_L2E, svp));
        esum += es;
        uint4 m0 = *(const uint4*)(mhb + (size_t)m*128 + l*8);
        uint4 m1 = *(const uint4*)(mhb + (size_t)m*128 + l*8 + 4);
        {
          #define RC_PAIR(MU, J) { \
            half2v hh = __builtin_bit_cast(half2v, MU); \
            cr[2*(J)]   = fmaf((float)hh[0], es, cr[2*(J)]); \
            cr[2*(J)+1] = fmaf((float)hh[1], es, cr[2*(J)+1]); }
          RC_PAIR(m0.x,0) RC_PAIR(m0.y,1) RC_PAIR(m0.z,2) RC_PAIR(m0.w,3)
          RC_PAIR(m1.x,4) RC_PAIR(m1.y,5) RC_PAIR(m1.z,6) RC_PAIR(m1.w,7)
          #undef RC_PAIR
        }
      }
      #pragma unroll
      for(int i=0;i<16;++i){
        cr[i] += __shfl_xor(cr[i], 16, 64);
        cr[i] += __shfl_xor(cr[i], 32, 64);
      }
      if(lane < 16){
        float* pp = part + wave*256 + l*16;
        *(float4*)(pp)      = make_float4(cr[0],  cr[1],  cr[2],  cr[3]);
        *(float4*)(pp + 4)  = make_float4(cr[4],  cr[5],  cr[6],  cr[7]);
        *(float4*)(pp + 8)  = make_float4(cr[8],  cr[9],  cr[10], cr[11]);
        *(float4*)(pp + 12) = make_float4(cr[12], cr[13], cr[14], cr[15]);
      }
      if(l == 0) esum_w[wave*4 + g] = esum;
    }
    __syncthreads();
    if(tid < 128){
      float rs = 0.f;
      #pragma unroll
      for(int i2=0;i2<64;++i2) rs += esum_w[i2];
      rs = rcpfast(rs);
      float lo = 0.f, hi = 0.f;
      #pragma unroll
      for(int w=0; w<16; ++w){
        lo += part[w*256 + 2*tid];
        hi += part[w*256 + 2*tid + 1];
      }
      c2[tid] = pkh2(lo*rs, hi*rs);
    }
    __syncthreads();
    if(tid < 768) gdot(768 + tid, c2);
    __syncthreads();
    if(tid < 256){
      const int j = tid;
      float hr  = ghgi[j]       + bh0;
      float hz  = ghgi[256 + j] + bh1;
      float hn  = ghgi[512 + j] + bh2v;
      float ir  = ghgi[1536 + j]       + ghgi[768 + j]       + bi0;
      float iz  = ghgi[1536 + 256 + j] + ghgi[768 + 256 + j] + bi1;
      float inn = ghgi[1536 + 512 + j] + ghgi[768 + 512 + j] + bi2;
      float r = rcpfast(1.f + exp2fast(-(ir + hr) * L2E));
      float z = rcpfast(1.f + exp2fast(-(iz + hz) * L2E));
      float narg = inn + r*hn;
      float n = 1.f - 2.f*rcpfast(1.f + exp2fast(narg * TWO_L2E));
      float hnew = (1.f - z)*n + z*h_l[j];
      h_l[j] = hnew;
      ys[((size_t)b*512 + tx)*512 + d*256 + j] = hnew;
    }
    __syncthreads();
    if(tid < 128){
      h2[tid] = pkh2(h_l[2*tid], h_l[2*tid + 1]);
    } else if(tid < 256 && step < 511){
      int t = tid - 128;
      int txn = d ? (511 - (step+1)) : (step+1);
      x2[t] = xhb[(size_t)txn*128 + t];
    }
    __syncthreads();
  }
}

// ---------------- final gate ----------------
__global__ void k_gate_h(const u16* __restrict__ G, float* __restrict__ ysb, int n4){
  int i = blockIdx.x*256 + threadIdx.x;
  if(i >= n4) return;
  ushort4 g = ((const ushort4*)G)[i];
  float4 y = ((const float4*)ysb)[i];
  float4 o;
  o.x = y.x * rcpfast(1.f + exp2fast(-h16f(g.x) * L2E));
  o.y = y.y * rcpfast(1.f + exp2fast(-h16f(g.y) * L2E));
  o.z = y.z * rcpfast(1.f + exp2fast(-h16f(g.z) * L2E));
  o.w = y.w * rcpfast(1.f + exp2fast(-h16f(g.w) * L2E));
  ((float4*)ysb)[i] = o;
}

// ---------------- host ----------------
extern "C" void kernel_launch(void* const* d_in, const int* in_sizes, int n_in,
                              void* d_out, int out_size, void* d_ws, size_t ws_size,
                              hipStream_t stream)
{
  int iIn=-1, iMem=-1, iW[3]={-1,-1,-1}, nW=0, iV=-1, iWih=-1, iWhh=-1,
      iBih=-1, iBhh=-1, iWg=-1;
  for(int i = 0; i < n_in; ++i){
    switch(in_sizes[i]){
      case 4194304: if(iIn < 0) iIn = i; else if(iMem < 0) iMem = i; break;
      case 131072:  if(nW < 3) iW[nW++] = i; break;
      case 512:     iV = i; break;
      case 786432:  iWih = i; break;
      case 393216:  iWhh = i; break;
      case 1536:    if(iBih < 0) iBih = i; else if(iBhh < 0) iBhh = i; break;
      case 262144:  iWg = i; break;
      default: break;
    }
  }
  bool ok = (iIn>=0 && iMem>=0 && nW==3 && iV>=0 && iWih>=0 && iWhh>=0 &&
             iBih>=0 && iBhh>=0 && iWg>=0);
  if(!ok){
    k_sentinelf<<<(out_size + 255)/256, 256, 0, stream>>>((float*)d_out, out_size, 42.0f);
    return;
  }

  char* ws = (char*)d_ws;
  size_t off = 0;
  auto alloc = [&](size_t bytes)->void*{
    void* pp = ws + off; off += (bytes + 255) & ~(size_t)255; return pp;
  };
  float* cxf   = (float*)alloc(4194304ull*4);
  float* cmemf = (float*)alloc(4194304ull*4);
  u16*   E16   = (u16*)  alloc(2ull*16384*256*2);
  u16*   qx16  = (u16*)  alloc(2ull*16384*256*2);
  u32*   memh2 = (u32*)  alloc(32ull*512*128*4);
  u32*   Wh2   = (u32*)  alloc(2ull*128*256*4);
  u32*   Wc2   = (u32*)  alloc(2ull*128*2304*4);
  float* Wmf   = (float*)alloc(131072ull*4);
  float* Wif   = (float*)alloc(131072ull*4);
  float* Wgf   = (float*)alloc(262144ull*4);
  float* cvf   = (float*)alloc(512ull*4);
  float* bihf  = (float*)alloc(1536ull*4);
  float* bhhf  = (float*)alloc(1536ull*4);
  int*   flag  = (int*)  alloc(256);
  size_t needA = (2ull*256*768*4 + 255 + 2ull*16384*768*2 + 255);
  bool useGix = (off + needA <= ws_size);
  float* WihT  = nullptr;
  u16*   gix16 = nullptr;
  u32*   xh2   = nullptr;
  if(useGix){
    WihT  = (float*)alloc(2ull*256*768*4);
    gix16 = (u16*)  alloc(2ull*16384*768*2);
  } else {
    xh2   = (u32*)  alloc(32ull*512*128*4);
  }
  if(off > ws_size){
    k_sentinelf<<<(out_size + 255)/256, 256, 0, stream>>>((float*)d_out, out_size, 43.0f);
    return;
  }

  k_detect<<<1, 256, 0, stream>>>((const u16*)d_in[iIn], 65536, flag);

  auto conv = [&](const void* src, float* dst, int n){
    k_convf<<<(n + 255)/256, 256, 0, stream>>>(src, dst, n, flag);
  };
  conv(d_in[iIn],   cxf,   4194304);
  conv(d_in[iMem],  cmemf, 4194304);
  conv(d_in[iW[0]], Wmf,   131072);
  conv(d_in[iW[1]], Wif,   131072);
  conv(d_in[iV],    cvf,   512);
  conv(d_in[iBih],  bihf,  1536);
  conv(d_in[iBhh],  bhhf,  1536);
  conv(d_in[iWg],   Wgf,   262144);
  k_pack_wh2<<<(2*128*256 + 255)/256, 256, 0, stream>>>(d_in[iW[2]], Wh2, flag);
  k_pack_wc2<<<(2*128*2304 + 255)/256, 256, 0, stream>>>(d_in[iWhh], d_in[iWih], Wc2, flag);
  k_pack_h2<<<(2097152 + 255)/256, 256, 0, stream>>>(d_in[iMem], memh2, 2097152, flag);
  if(!useGix)
    k_pack_h2<<<(2097152 + 255)/256, 256, 0, stream>>>(d_in[iIn], xh2, 2097152, flag);
  else
    k_pack_wiht<<<(2*256*768 + 255)/256, 256, 0, stream>>>(d_in[iWih], WihT, flag);

  for(int dd = 0; dd < 2; ++dd){
    k_gemm_h16<1><<<dim3(256, 4), 256, 0, stream>>>(
        cmemf, 256, Wmf + (size_t)dd*65536, 256,
        E16 + (size_t)dd*16384*256, 256, 256);
    k_gemm_h16<0><<<dim3(256, 4), 256, 0, stream>>>(
        cxf, 256, Wif + (size_t)dd*65536, 256,
        qx16 + (size_t)dd*16384*256, 256, 256);
    if(useGix)
      k_gemm_h16<0><<<dim3(256, 12), 256, 0, stream>>>(
          cxf, 256, WihT + (size_t)dd*196608, 768,
          gix16 + (size_t)dd*16384*768, 768, 256);
  }

  if(useGix){
    (void)hipFuncSetAttribute((const void*)k_scan7,
                              hipFuncAttributeMaxDynamicSharedMemorySize, SCAN7_LDS);
    k_scan7<<<64, 1024, SCAN7_LDS, stream>>>(E16, qx16, Wh2, Wc2, gix16, memh2,
                                             cvf, bihf, bhhf, (float*)d_out);
  } else {
    k_scan5b<<<64, 1024, 0, stream>>>(E16, qx16, Wh2, Wc2, xh2, memh2,
                                      cvf, bihf, bhhf, (float*)d_out);
  }

  u16* G16 = (u16*)cxf;
  k_gemm_h16<0><<<dim3(256, 8), 256, 0, stream>>>(
      (const float*)d_out, 512, Wgf, 512, G16, 512, 512);
  k_gate_h<<<(8388608/4 + 255)/256, 256, 0, stream>>>(G16, (float*)d_out, 8388608/4);
}

// Round 14
// 10186.318 us; speedup vs baseline: 4.2859x; 4.2859x over previous
//
#include <hip/hip_runtime.h>
#include <stdint.h>

typedef unsigned short u16;
typedef unsigned int   u32;
typedef _Float16 half2v __attribute__((ext_vector_type(2)));

#define L2E 1.4426950408889634f
#define TWO_L2E 2.8853900817779268f

__device__ __forceinline__ float bf2f(u16 b){ return __uint_as_float(((u32)b) << 16); }
__device__ __forceinline__ float ldf(const void* p, size_t i, int flag){
  return flag ? ((const float*)p)[i] : bf2f(((const u16*)p)[i]);
}
__device__ __forceinline__ float rcpfast(float x){
#if __has_builtin(__builtin_amdgcn_rcpf)
  return __builtin_amdgcn_rcpf(x);
#else
  return 1.0f / x;
#endif
}
__device__ __forceinline__ float exp2fast(float x){
#if __has_builtin(__builtin_amdgcn_exp2f)
  return __builtin_amdgcn_exp2f(x);
#else
  return exp2f(x);
#endif
}
__device__ __forceinline__ float fdot2f(u32 a, u32 b, float c){
#if __has_builtin(__builtin_amdgcn_fdot2)
  return __builtin_amdgcn_fdot2(__builtin_bit_cast(half2v, a), __builtin_bit_cast(half2v, b), c, false);
#else
  half2v ha = __builtin_bit_cast(half2v, a), hb = __builtin_bit_cast(half2v, b);
  return c + (float)ha[0]*(float)hb[0] + (float)ha[1]*(float)hb[1];
#endif
}
__device__ __forceinline__ u32 pkh2(float lo, float hi){
  half2v h; h[0] = (_Float16)lo; h[1] = (_Float16)hi;
  return __builtin_bit_cast(u32, h);
}
__device__ __forceinline__ u16 f2h16(float f){
  _Float16 h = (_Float16)f;
  return __builtin_bit_cast(u16, h);
}
__device__ __forceinline__ float h16f(u16 h){
  return (float)__builtin_bit_cast(_Float16, h);
}

// ---------------- sentinel ----------------
__global__ void k_sentinelf(float* __restrict__ out, int n, float val){
  int i = blockIdx.x*256 + threadIdx.x;
  if(i < n) out[i] = val;
}

// ---------------- dtype detection + canonicalize ----------------
__global__ void k_detect(const u16* __restrict__ p, int n, int* __restrict__ flag){
  __shared__ int cnt;
  if(threadIdx.x == 0) cnt = 0;
  __syncthreads();
  int c = 0;
  for(int i = threadIdx.x; i < n; i += 256){
    int e = (p[i] >> 7) & 0xFF;
    c += (e >= 112 && e <= 142) ? 1 : 0;
  }
  atomicAdd(&cnt, c);
  __syncthreads();
  if(threadIdx.x == 0) *flag = (cnt >= (n/10)*9) ? 0 : 1;
}
__global__ void k_convf(const void* __restrict__ src, float* __restrict__ dst, int n,
                        const int* __restrict__ flag){
  int i = blockIdx.x*256 + threadIdx.x;
  if(i < n) dst[i] = ldf(src, i, *flag);
}

// ---------------- packs ----------------
__global__ void k_pack_wh2(const void* __restrict__ Wh, u32* __restrict__ out,
                           const int* __restrict__ flag){
  int i = blockIdx.x*256 + threadIdx.x;
  if(i >= 2*128*256) return;
  int d = i >> 15, k2 = (i >> 8) & 127, a = i & 255;
  float lo = ldf(Wh, ((size_t)d*256 + 2*k2    )*256 + a, *flag);
  float hi = ldf(Wh, ((size_t)d*256 + 2*k2 + 1)*256 + a, *flag);
  out[i] = pkh2(lo, hi);
}
__global__ void k_pack_wc2(const void* __restrict__ Whh, const void* __restrict__ Wih,
                           u32* __restrict__ out, const int* __restrict__ flag){
  int i = blockIdx.x*256 + threadIdx.x;
  if(i >= 2*128*2304) return;
  int d = i / (128*2304), r = i % (128*2304);
  int k2 = r / 2304, j = r % 2304;
  int k = 2*k2;
  float lo, hi;
  if(j < 768){
    lo = ldf(Whh, ((size_t)d*768 + j)*256 + k,     *flag);
    hi = ldf(Whh, ((size_t)d*768 + j)*256 + k + 1, *flag);
  } else if(j < 1536){
    lo = ldf(Wih, ((size_t)d*768 + (j-768))*512 + 256 + k,     *flag);
    hi = ldf(Wih, ((size_t)d*768 + (j-768))*512 + 256 + k + 1, *flag);
  } else {
    lo = ldf(Wih, ((size_t)d*768 + (j-1536))*512 + k,     *flag);
    hi = ldf(Wih, ((size_t)d*768 + (j-1536))*512 + k + 1, *flag);
  }
  out[i] = pkh2(lo, hi);
}
__global__ void k_pack_h2(const void* __restrict__ src, u32* __restrict__ out, int n2,
                          const int* __restrict__ flag){
  int i = blockIdx.x*256 + threadIdx.x;
  if(i >= n2) return;
  out[i] = pkh2(ldf(src, 2*(size_t)i, *flag), ldf(src, 2*(size_t)i + 1, *flag));
}
__global__ void k_pack_wiht(const void* __restrict__ Wih, float* __restrict__ out,
                            const int* __restrict__ flag){
  int i = blockIdx.x*256 + threadIdx.x;
  if(i >= 2*256*768) return;
  int d = i / 196608, r = i % 196608;
  int k = r / 768, j = r % 768;
  out[i] = ldf(Wih, ((size_t)d*768 + j)*512 + k, *flag);
}

// ---------------- GEMM C = A@B, fp16 out. MODE 0: plain; MODE 1: clamp(exp2(v*2log2e)) ----
template<int MODE>
__global__ __launch_bounds__(256)
void k_gemm_h16(const float* __restrict__ A, int lda,
                const float* __restrict__ B, int ldb,
                u16* __restrict__ C, int N, int K)
{
  __shared__ float As[64][17];
  __shared__ float Bs[16][65];
  const int m0 = blockIdx.x * 64, n0 = blockIdx.y * 64;
  const int tid = threadIdx.x;
  const int arow = tid >> 2, acol = (tid & 3) * 4;
  const int brow = tid >> 4, bcol = (tid & 15) * 4;
  const int ty = tid >> 4, tx = tid & 15;
  float acc[4][4];
  #pragma unroll
  for(int i=0;i<4;++i)
    #pragma unroll
    for(int j=0;j<4;++j) acc[i][j] = 0.f;
  for(int k0 = 0; k0 < K; k0 += 16){
    float4 a4 = *(const float4*)(A + (size_t)(m0 + arow)*lda + k0 + acol);
    As[arow][acol+0] = a4.x; As[arow][acol+1] = a4.y;
    As[arow][acol+2] = a4.z; As[arow][acol+3] = a4.w;
    float4 b4 = *(const float4*)(B + (size_t)(k0 + brow)*ldb + n0 + bcol);
    Bs[brow][bcol+0] = b4.x; Bs[brow][bcol+1] = b4.y;
    Bs[brow][bcol+2] = b4.z; Bs[brow][bcol+3] = b4.w;
    __syncthreads();
    #pragma unroll
    for(int kk = 0; kk < 16; ++kk){
      float ar[4], br[4];
      #pragma unroll
      for(int i=0;i<4;++i) ar[i] = As[ty*4+i][kk];
      #pragma unroll
      for(int j=0;j<4;++j) br[j] = Bs[kk][tx*4+j];
      #pragma unroll
      for(int i=0;i<4;++i)
        #pragma unroll
        for(int j=0;j<4;++j) acc[i][j] = fmaf(ar[i], br[j], acc[i][j]);
    }
    __syncthreads();
  }
  #pragma unroll
  for(int i=0;i<4;++i)
    #pragma unroll
    for(int j=0;j<4;++j){
      float v = acc[i][j];
      if(MODE==1){ v = exp2fast(v * TWO_L2E); v = fminf(v, 65504.f); }
      C[(size_t)(m0 + ty*4 + i)*N + n0 + tx*4 + j] = f2h16(v);
    }
}

// ---------------- recurrent scan v5 (R11 champion, verbatim) ----------------
template<int USE_GIX>
__global__ __launch_bounds__(1024)
void k_scan5(const u16* __restrict__ E16,    // [2][16384][256] fp16 e^{2P} clamped
             const u16* __restrict__ qx16,   // [2][16384][256] fp16 x@Wi
             const u32* __restrict__ Wh2,    // [2][128][256]
             const u32* __restrict__ Wc2,    // [2][128][2304]
             const u32* __restrict__ xh2,    // [32][512][128] (variant B only)
             const u16* __restrict__ gix16,  // [2][16384][768] (variant A only)
             const u32* __restrict__ memh2,  // [32][512][128]
             const float* __restrict__ vf,
             const float* __restrict__ bihf,
             const float* __restrict__ bhhf,
             float* __restrict__ ys)         // [32][512][512] f32 = d_out
{
  __shared__ float h_l[256];
  __shared__ __align__(16) u32 h2[128];
  __shared__ __align__(16) u32 c2[128];
  __shared__ __align__(16) u32 x2[128];
  __shared__ __align__(16) float F[256];
  __shared__ __align__(16) float part[4096];
  __shared__ float ghgi[2304];
  __shared__ float esum_w[64];
  __shared__ float svp_sh;

  const int tid = threadIdx.x;
  const int p = blockIdx.x, d = p >> 5, b = p & 31;
  const int lane = tid & 63, wave = tid >> 6;
  const int g = lane >> 4, l = lane & 15;

  const u16* Eb   = E16  + ((size_t)d*16384 + (size_t)b*512)*256;
  const u16* qxb  = qx16 + ((size_t)d*16384 + (size_t)b*512)*256;
  const u32* Whd  = Wh2  + (size_t)d*128*256;
  const u32* Wcd  = Wc2  + (size_t)d*128*2304;
  const u32* xhb  = xh2  + (size_t)b*512*128;
  const u16* gixb = gix16 + ((size_t)d*16384 + (size_t)b*512)*768;
  const u32* mhb  = memh2 + (size_t)b*512*128;

  // prologue
  if(tid < 256){ h_l[tid] = 0.f; part[tid] = vf[d*256 + tid]; }
  if(tid < 128){
    h2[tid] = 0u;
    if(!USE_GIX){
      int tx0 = d ? 511 : 0;
      x2[tid] = xhb[(size_t)tx0*128 + tid];
    }
  }
  float vr[16];
  {
    const float* vp = vf + d*256 + l*16;
    *(float4*)&vr[0]  = *(const float4*)(vp);
    *(float4*)&vr[4]  = *(const float4*)(vp + 4);
    *(float4*)&vr[8]  = *(const float4*)(vp + 8);
    *(float4*)&vr[12] = *(const float4*)(vp + 12);
  }
  float bh0=0,bh1=0,bh2v=0,bi0=0,bi1=0,bi2=0;
  if(tid < 256){
    bh0  = bhhf[d*768 + tid];       bi0 = bihf[d*768 + tid];
    bh1  = bhhf[d*768 + 256 + tid]; bi1 = bihf[d*768 + 256 + tid];
    bh2v = bhhf[d*768 + 512 + tid]; bi2 = bihf[d*768 + 512 + tid];
  }
  __syncthreads();
  if(tid == 0){ float s=0.f; for(int i=0;i<256;++i) s += part[i]; svp_sh = s * L2E; }
  __syncthreads();

  auto gdot = [&](int col, const u32* s2){
    const u32* wp = Wcd + col;
    float a0=0.f, a1=0.f, a2=0.f, a3=0.f;
    #pragma unroll 4
    for(int k0=0;k0<32;++k0){
      uint4 s4 = *(const uint4*)&s2[4*k0];
      a0 = fdot2f(wp[(size_t)(4*k0    )*2304], s4.x, a0);
      a1 = fdot2f(wp[(size_t)(4*k0 + 1)*2304], s4.y, a1);
      a2 = fdot2f(wp[(size_t)(4*k0 + 2)*2304], s4.z, a2);
      a3 = fdot2f(wp[(size_t)(4*k0 + 3)*2304], s4.w, a3);
    }
    ghgi[col] = (a0+a1)+(a2+a3);
  };

  for(int step = 0; step < 512; ++step){
    const int tx = d ? (511 - step) : step;

    // S0: R_Q — q partials (h@Wh). kq=tid>>8 (4 quarters of 32 k2)
    {
      const int a = tid & 255, kq = tid >> 8;
      const u32* wp = Whd + (size_t)(kq*32)*256 + a;
      float q0=0.f,q1=0.f,q2=0.f,q3=0.f;
      #pragma unroll
      for(int i0=0;i0<8;++i0){
        uint4 hv = *(const uint4*)&h2[kq*32 + 4*i0];
        q0 = fdot2f(wp[(size_t)(4*i0    )*256], hv.x, q0);
        q1 = fdot2f(wp[(size_t)(4*i0 + 1)*256], hv.y, q1);
        q2 = fdot2f(wp[(size_t)(4*i0 + 2)*256], hv.z, q2);
        q3 = fdot2f(wp[(size_t)(4*i0 + 3)*256], hv.w, q3);
      }
      part[kq*256 + a] = (q0+q1)+(q2+q3);
    }
    __syncthreads();
    // S1: F = e^{2q}
    if(tid < 256){
      float q = h16f(qxb[(size_t)tx*256 + tid])
              + part[tid] + part[256+tid] + part[512+tid] + part[768+tid];
      F[tid] = exp2fast(q * TWO_L2E);
    }
    __syncthreads();

    // S2: gemv h-cols (+x-cols in variant B) overlapped with R_A
    {
      if(tid < 768) gdot(tid, h2);
      if(!USE_GIX){
        if(tid >= 768) gdot(1536 + (tid - 768), x2);
        if(tid < 512)  gdot(1792 + tid, x2);
      }

      // R_A: group g owns row m = wave*32 + it*4 + g; lane-l owns a = l*16..l*16+15
      float Fr[16];
      {
        const float* fp = F + l*16;
        *(float4*)&Fr[0]  = *(const float4*)(fp);
        *(float4*)&Fr[4]  = *(const float4*)(fp + 4);
        *(float4*)&Fr[8]  = *(const float4*)(fp + 8);
        *(float4*)&Fr[12] = *(const float4*)(fp + 12);
      }
      float cr[16];
      #pragma unroll
      for(int i=0;i<16;++i) cr[i] = 0.f;
      float esum = 0.f;
      const float svp = svp_sh;

      #pragma unroll 2
      for(int it=0; it<8; ++it){
        const int m = wave*32 + it*4 + g;
        uint4 e0 = *(const uint4*)(Eb + (size_t)m*256 + l*16);
        uint4 e1 = *(const uint4*)(Eb + (size_t)m*256 + l*16 + 8);
        float u = 0.f;
        {
          #define RA_PAIR(EU, J) { \
            half2v hh = __builtin_bit_cast(half2v, EU); \
            float t0 = rcpfast(fmaf((float)hh[0], Fr[2*(J)],   1.f)); \
            float t1 = rcpfast(fmaf((float)hh[1], Fr[2*(J)+1], 1.f)); \
            u = fmaf(vr[2*(J)], t0, u); u = fmaf(vr[2*(J)+1], t1, u); }
          RA_PAIR(e0.x,0) RA_PAIR(e0.y,1) RA_PAIR(e0.z,2) RA_PAIR(e0.w,3)
          RA_PAIR(e1.x,4) RA_PAIR(e1.y,5) RA_PAIR(e1.z,6) RA_PAIR(e1.w,7)
          #undef RA_PAIR
        }
        u += __shfl_xor(u, 1, 64);
        u += __shfl_xor(u, 2, 64);
        u += __shfl_xor(u, 4, 64);
        u += __shfl_xor(u, 8, 64);
        float es = exp2fast(fmaf(u, -TWO_L2E, svp));
        esum += es;
        uint4 m0 = *(const uint4*)(mhb + (size_t)m*128 + l*8);
        uint4 m1 = *(const uint4*)(mhb + (size_t)m*128 + l*8 + 4);
        {
          #define RC_PAIR(MU, J) { \
            half2v hh = __builtin_bit_cast(half2v, MU); \
            cr[2*(J)]   = fmaf((float)hh[0], es, cr[2*(J)]); \
            cr[2*(J)+1] = fmaf((float)hh[1], es, cr[2*(J)+1]); }
          RC_PAIR(m0.x,0) RC_PAIR(m0.y,1) RC_PAIR(m0.z,2) RC_PAIR(m0.w,3)
          RC_PAIR(m1.x,4) RC_PAIR(m1.y,5) RC_PAIR(m1.z,6) RC_PAIR(m1.w,7)
          #undef RC_PAIR
        }
      }
      #pragma unroll
      for(int i=0;i<16;++i){
        cr[i] += __shfl_xor(cr[i], 16, 64);
        cr[i] += __shfl_xor(cr[i], 32, 64);
      }
      if(lane < 16){
        float* pp = part + wave*256 + l*16;
        *(float4*)(pp)      = make_float4(cr[0],  cr[1],  cr[2],  cr[3]);
        *(float4*)(pp + 4)  = make_float4(cr[4],  cr[5],  cr[6],  cr[7]);
        *(float4*)(pp + 8)  = make_float4(cr[8],  cr[9],  cr[10], cr[11]);
        *(float4*)(pp + 12) = make_float4(cr[12], cr[13], cr[14], cr[15]);
      }
      if(l == 0) esum_w[wave*4 + g] = esum;
    }
    __syncthreads();

    // S3: combine c + pack c2 (tid<128, 2 columns each)
    if(tid < 128){
      float rs = 0.f;
      #pragma unroll
      for(int i2=0;i2<64;++i2) rs += esum_w[i2];
      rs = rcpfast(rs);
      float lo = 0.f, hi = 0.f;
      #pragma unroll
      for(int w=0; w<16; ++w){
        lo += part[w*256 + 2*tid];
        hi += part[w*256 + 2*tid + 1];
      }
      c2[tid] = pkh2(lo*rs, hi*rs);
    }
    __syncthreads();

    // S4: gemv c-cols (768)
    if(tid < 768) gdot(768 + tid, c2);
    __syncthreads();

    // S5: gates + h update
    if(tid < 256){
      const int j = tid;
      float hr  = ghgi[j]       + bh0;
      float hz  = ghgi[256 + j] + bh1;
      float hn  = ghgi[512 + j] + bh2v;
      float ir, iz, inn;
      if(USE_GIX){
        const u16* gxp = gixb + (size_t)tx*768;
        ir  = ghgi[768 + j]       + h16f(gxp[j])       + bi0;
        iz  = ghgi[768 + 256 + j] + h16f(gxp[256 + j]) + bi1;
        inn = ghgi[768 + 512 + j] + h16f(gxp[512 + j]) + bi2;
      } else {
        ir  = ghgi[1536 + j]       + ghgi[768 + j]       + bi0;
        iz  = ghgi[1536 + 256 + j] + ghgi[768 + 256 + j] + bi1;
        inn = ghgi[1536 + 512 + j] + ghgi[768 + 512 + j] + bi2;
      }
      float r = rcpfast(1.f + exp2fast(-(ir + hr) * L2E));
      float z = rcpfast(1.f + exp2fast(-(iz + hz) * L2E));
      float narg = inn + r*hn;
      float n = 1.f - 2.f*rcpfast(1.f + exp2fast(narg * TWO_L2E));
      float hnew = (1.f - z)*n + z*h_l[j];
      h_l[j] = hnew;
      ys[((size_t)b*512 + tx)*512 + d*256 + j] = hnew;
    }
    __syncthreads();

    // S6: pack h2 (+ next x2 in variant B)
    if(tid < 128){
      h2[tid] = pkh2(h_l[2*tid], h_l[2*tid + 1]);
    } else if(!USE_GIX && tid < 256 && step < 511){
      int t = tid - 128;
      int txn = d ? (511 - (step+1)) : (step+1);
      x2[t] = xhb[(size_t)txn*128 + t];
    }
    __syncthreads();
  }
}

// ---------------- final gate ----------------
__global__ void k_gate_h(const u16* __restrict__ G, float* __restrict__ ysb, int n4){
  int i = blockIdx.x*256 + threadIdx.x;
  if(i >= n4) return;
  ushort4 g = ((const ushort4*)G)[i];
  float4 y = ((const float4*)ysb)[i];
  float4 o;
  o.x = y.x * rcpfast(1.f + exp2fast(-h16f(g.x) * L2E));
  o.y = y.y * rcpfast(1.f + exp2fast(-h16f(g.y) * L2E));
  o.z = y.z * rcpfast(1.f + exp2fast(-h16f(g.z) * L2E));
  o.w = y.w * rcpfast(1.f + exp2fast(-h16f(g.w) * L2E));
  ((float4*)ysb)[i] = o;
}

// ---------------- host ----------------
extern "C" void kernel_launch(void* const* d_in, const int* in_sizes, int n_in,
                              void* d_out, int out_size, void* d_ws, size_t ws_size,
                              hipStream_t stream)
{
  int iIn=-1, iMem=-1, iW[3]={-1,-1,-1}, nW=0, iV=-1, iWih=-1, iWhh=-1,
      iBih=-1, iBhh=-1, iWg=-1;
  for(int i = 0; i < n_in; ++i){
    switch(in_sizes[i]){
      case 4194304: if(iIn < 0) iIn = i; else if(iMem < 0) iMem = i; break;
      case 131072:  if(nW < 3) iW[nW++] = i; break;
      case 512:     iV = i; break;
      case 786432:  iWih = i; break;
      case 393216:  iWhh = i; break;
      case 1536:    if(iBih < 0) iBih = i; else if(iBhh < 0) iBhh = i; break;
      case 262144:  iWg = i; break;
      default: break;
    }
  }
  bool ok = (iIn>=0 && iMem>=0 && nW==3 && iV>=0 && iWih>=0 && iWhh>=0 &&
             iBih>=0 && iBhh>=0 && iWg>=0);
  if(!ok){
    k_sentinelf<<<(out_size + 255)/256, 256, 0, stream>>>((float*)d_out, out_size, 42.0f);
    return;
  }

  char* ws = (char*)d_ws;
  size_t off = 0;
  auto alloc = [&](size_t bytes)->void*{
    void* pp = ws + off; off += (bytes + 255) & ~(size_t)255; return pp;
  };
  float* cxf   = (float*)alloc(4194304ull*4);
  float* cmemf = (float*)alloc(4194304ull*4);
  u16*   E16   = (u16*)  alloc(2ull*16384*256*2);
  u16*   qx16  = (u16*)  alloc(2ull*16384*256*2);
  u32*   memh2 = (u32*)  alloc(32ull*512*128*4);
  u32*   Wh2   = (u32*)  alloc(2ull*128*256*4);
  u32*   Wc2   = (u32*)  alloc(2ull*128*2304*4);
  float* Wmf   = (float*)alloc(131072ull*4);
  float* Wif   = (float*)alloc(131072ull*4);
  float* Wgf   = (float*)alloc(262144ull*4);
  float* cvf   = (float*)alloc(512ull*4);
  float* bihf  = (float*)alloc(1536ull*4);
  float* bhhf  = (float*)alloc(1536ull*4);
  int*   flag  = (int*)  alloc(256);
  size_t needA = (2ull*256*768*4 + 255 + 2ull*16384*768*2 + 255);
  bool useGix = (off + needA <= ws_size);
  float* WihT  = nullptr;
  u16*   gix16 = nullptr;
  u32*   xh2   = nullptr;
  if(useGix){
    WihT  = (float*)alloc(2ull*256*768*4);
    gix16 = (u16*)  alloc(2ull*16384*768*2);
  } else {
    xh2   = (u32*)  alloc(32ull*512*128*4);
  }
  if(off > ws_size){
    k_sentinelf<<<(out_size + 255)/256, 256, 0, stream>>>((float*)d_out, out_size, 43.0f);
    return;
  }

  k_detect<<<1, 256, 0, stream>>>((const u16*)d_in[iIn], 65536, flag);

  auto conv = [&](const void* src, float* dst, int n){
    k_convf<<<(n + 255)/256, 256, 0, stream>>>(src, dst, n, flag);
  };
  conv(d_in[iIn],   cxf,   4194304);
  conv(d_in[iMem],  cmemf, 4194304);
  conv(d_in[iW[0]], Wmf,   131072);
  conv(d_in[iW[1]], Wif,   131072);
  conv(d_in[iV],    cvf,   512);
  conv(d_in[iBih],  bihf,  1536);
  conv(d_in[iBhh],  bhhf,  1536);
  conv(d_in[iWg],   Wgf,   262144);
  k_pack_wh2<<<(2*128*256 + 255)/256, 256, 0, stream>>>(d_in[iW[2]], Wh2, flag);
  k_pack_wc2<<<(2*128*2304 + 255)/256, 256, 0, stream>>>(d_in[iWhh], d_in[iWih], Wc2, flag);
  k_pack_h2<<<(2097152 + 255)/256, 256, 0, stream>>>(d_in[iMem], memh2, 2097152, flag);
  if(!useGix)
    k_pack_h2<<<(2097152 + 255)/256, 256, 0, stream>>>(d_in[iIn], xh2, 2097152, flag);
  else
    k_pack_wiht<<<(2*256*768 + 255)/256, 256, 0, stream>>>(d_in[iWih], WihT, flag);

  for(int dd = 0; dd < 2; ++dd){
    k_gemm_h16<1><<<dim3(256, 4), 256, 0, stream>>>(
        cmemf, 256, Wmf + (size_t)dd*65536, 256,
        E16 + (size_t)dd*16384*256, 256, 256);
    k_gemm_h16<0><<<dim3(256, 4), 256, 0, stream>>>(
        cxf, 256, Wif + (size_t)dd*65536, 256,
        qx16 + (size_t)dd*16384*256, 256, 256);
    if(useGix)
      k_gemm_h16<0><<<dim3(256, 12), 256, 0, stream>>>(
          cxf, 256, WihT + (size_t)dd*196608, 768,
          gix16 + (size_t)dd*16384*768, 768, 256);
  }

  if(useGix)
    k_scan5<1><<<64, 1024, 0, stream>>>(E16, qx16, Wh2, Wc2, nullptr, gix16, memh2,
                                        cvf, bihf, bhhf, (float*)d_out);
  else
    k_scan5<0><<<64, 1024, 0, stream>>>(E16, qx16, Wh2, Wc2, xh2, nullptr, memh2,
                                        cvf, bihf, bhhf, (float*)d_out);

  u16* G16 = (u16*)cxf;
  k_gemm_h16<0><<<dim3(256, 8), 256, 0, stream>>>(
      (const float*)d_out, 512, Wgf, 512, G16, 512, 512);
  k_gate_h<<<(8388608/4 + 255)/256, 256, 0, stream>>>(G16, (float*)d_out, 8388608/4);
}